// Round 10
// baseline (234.825 us; speedup 1.0000x reference)
//
#include <hip/hip_runtime.h>

// Problem constants
#define BB 256
#define NN 5
#define EPSF 1e-8f
#define TPB 1024
#define FAN 8                 // members (blocks) per set, one oc-chunk each
#define NSETS 32              // concurrent b's
#define NIT 8                 // iterations: 256 / 32
#define CNT_STRIDE 32         // ints -> 128 B per counter (own cache line)
#define PART_STRIDE 16        // floats per (b,member) slot -> 64 B

typedef float f4 __attribute__((ext_vector_type(4)));

// One-read cooperative kernel v2. grid = 256 x 1024, 1 block/CU (all resident).
// Set = 8 blocks with bid % 8 == xcd (same XCD under RR mapping -> fast L2-local
// sync; correctness does not depend on the mapping). Member m owns channels
// [80m, 80m+80) of all 5 shots of b = set + 32*it.
// Per iteration: regs->LDS, pool from LDS, partial stats, padded post+counter,
// prefetch next chunk to regs (hides under spin), spin+gather+sim (thread 0),
// weighted sum from LDS with NT store. x is read from global EXACTLY ONCE.
__global__ __launch_bounds__(TPB, 4) void k_coop(const float* __restrict__ x,
                                                 float* __restrict__ out,
                                                 float* __restrict__ g_part,
                                                 int* __restrict__ g_cnt) {
    __shared__ f4 xw[10000];            // 160,000 B: piece n at n*2000 f4
    __shared__ float feats_l[NN][100];  // 2,000 B: pooled dims (member-local)
    __shared__ float red[2][11];        // wave partials
    __shared__ float s_sim[NN];

    const int tid = threadIdx.x;
    const int bid = blockIdx.x;
    const int xcd = bid & 7;
    const int j   = bid >> 3;           // 0..31 within (assumed) XCD
    const int k4  = j & 3;
    const int m   = j >> 2;             // member 0..7
    const int set = xcd + 8 * k4;       // 0..31

    const f4* __restrict__ xg = reinterpret_cast<const f4*>(x);

    // ---- prologue: prefetch chunk for it=0 into registers ----
    f4 rr[10];
    if (tid < 1000) {
        #pragma unroll
        for (int q = 0; q < 10; ++q) {
            const int n = q >> 1, p = q & 1;
            rr[q] = xg[((size_t)(set * NN + n)) * 16000 + m * 2000 + p * 1000 + tid];
        }
    }

    for (int it = 0; it < NIT; ++it) {
        const int b = set + NSETS * it;

        // ---- stage registers -> LDS ----
        if (tid < 1000) {
            #pragma unroll
            for (int q = 0; q < 10; ++q)
                xw[(q >> 1) * 2000 + (q & 1) * 1000 + tid] = rr[q];
        }
        __syncthreads();

        // ---- pool: 500 threads, one (n, d-local) cell each ----
        if (tid < 500) {
            const int n  = tid / 100;
            const int dl = tid - n * 100;           // ocl*25 + oh*5 + ow
            const int ocl = dl / 25;
            const int r25 = dl - ocl * 25;
            const int oh  = r25 / 5;
            const int ow  = r25 - oh * 5;
            const float* __restrict__ xf = reinterpret_cast<const float*>(xw);
            const float* __restrict__ bp =
                xf + n * 8000 + (ocl * 20) * 100 + oh * 20 + ow * 2;
            float s = 0.f;
            #pragma unroll
            for (int cc = 0; cc < 20; ++cc) {
                const float* q = bp + cc * 100;
                s += (q[0] + q[1]) + (q[10] + q[11]);
            }
            feats_l[n][dl] = s * (1.f / 80.f);
        }
        __syncthreads();

        // ---- local partials over this member's 100 d-dims ----
        if (tid < 128) {
            float part[11];
            #pragma unroll
            for (int k = 0; k < 11; ++k) part[k] = 0.f;
            if (tid < 100) {
                float f[NN], p = 0.f;
                #pragma unroll
                for (int q = 0; q < NN; ++q) { f[q] = feats_l[q][tid]; p += f[q]; }
                #pragma unroll
                for (int q = 0; q < NN; ++q) { part[q] = f[q] * p; part[5 + q] = f[q] * f[q]; }
                part[10] = p * p;
            }
            #pragma unroll
            for (int off = 32; off >= 1; off >>= 1)
                #pragma unroll
                for (int k = 0; k < 11; ++k)
                    part[k] += __shfl_down(part[k], off, 64);
            if ((tid & 63) == 0) {
                #pragma unroll
                for (int k = 0; k < 11; ++k) red[tid >> 6][k] = part[k];
            }
        }
        __syncthreads();

        // ---- prefetch next chunk into regs (latency hides under spin) ----
        if (it + 1 < NIT && tid < 1000) {
            const int b2 = set + NSETS * (it + 1);
            #pragma unroll
            for (int q = 0; q < 10; ++q) {
                const int n = q >> 1, p = q & 1;
                rr[q] = xg[((size_t)(b2 * NN + n)) * 16000 + m * 2000 + p * 1000 + tid];
            }
        }

        // ---- post partials, spin to fan-in, gather, sim (thread 0) ----
        if (tid == 0) {
            #pragma unroll
            for (int k = 0; k < 11; ++k) {
                const float v = red[0][k] + red[1][k];
                __hip_atomic_store(&g_part[((size_t)b * FAN + m) * PART_STRIDE + k], v,
                                   __ATOMIC_RELAXED, __HIP_MEMORY_SCOPE_AGENT);
            }
            __hip_atomic_fetch_add(&g_cnt[(size_t)b * CNT_STRIDE], 1,
                                   __ATOMIC_RELEASE, __HIP_MEMORY_SCOPE_AGENT);
            while (__hip_atomic_load(&g_cnt[(size_t)b * CNT_STRIDE],
                                     __ATOMIC_ACQUIRE, __HIP_MEMORY_SCOPE_AGENT) < FAN)
                __builtin_amdgcn_s_sleep(4);
            float tot[11];
            #pragma unroll
            for (int k = 0; k < 11; ++k) tot[k] = 0.f;
            for (int mm = 0; mm < FAN; ++mm) {
                #pragma unroll
                for (int k = 0; k < 11; ++k)
                    tot[k] += __hip_atomic_load(
                        &g_part[((size_t)b * FAN + mm) * PART_STRIDE + k],
                        __ATOMIC_RELAXED, __HIP_MEMORY_SCOPE_AGENT);
            }
            const float nb = sqrtf(tot[10]);
            #pragma unroll
            for (int q = 0; q < NN; ++q)
                s_sim[q] = tot[q] / fmaxf(sqrtf(tot[5 + q]) * nb, EPSF);
        }
        __syncthreads();

        // ---- Phase C: out chunk from LDS, coalesced NT store ----
        if (tid < 1000) {
            const float w0 = s_sim[0], w1 = s_sim[1], w2 = s_sim[2],
                        w3 = s_sim[3], w4 = s_sim[4];
            f4* __restrict__ og = reinterpret_cast<f4*>(out) +
                                  (size_t)b * 16000 + m * 2000;
            #pragma unroll
            for (int h = 0; h < 2; ++h) {
                const int idx = h * 1000 + tid;
                f4 o = w0 * xw[idx]
                     + w1 * xw[2000 + idx]
                     + w2 * xw[4000 + idx]
                     + w3 * xw[6000 + idx]
                     + w4 * xw[8000 + idx];
                __builtin_nontemporal_store(o, og + idx);
            }
        }
        __syncthreads();   // xw consumed; next iteration may overwrite
    }
}

extern "C" void kernel_launch(void* const* d_in, const int* in_sizes, int n_in,
                              void* d_out, int out_size, void* d_ws, size_t ws_size,
                              hipStream_t stream) {
    const float* x = (const float*)d_in[0];
    float* out = (float*)d_out;
    // ws layout: g_cnt [256 * 32 ints = 32 KB] | g_part [256*8*16 floats = 128 KB]
    int* g_cnt = (int*)d_ws;
    float* g_part = (float*)((char*)d_ws + (size_t)BB * CNT_STRIDE * sizeof(int));
    hipMemsetAsync(d_ws, 0,
                   (size_t)BB * CNT_STRIDE * sizeof(int) +
                   (size_t)BB * FAN * PART_STRIDE * sizeof(float), stream);
    k_coop<<<BB, TPB, 0, stream>>>(x, out, g_part, g_cnt);
}